// Round 9
// baseline (1133.913 us; speedup 1.0000x reference)
//
#include <hip/hip_runtime.h>
#include <stdint.h>

// SpikingLinearLayer: spikes = LIF_scan(x @ W^T)  -- exact i8-limb MFMA path.
//   x: [20, 1024, 2048] fp32 binary; W: [2048, 2048] fp32; out fp32 binary.
//
// R8 -> R9: NO LDS, NO BARRIERS. R4==R7 (~490 us, MfmaUtil 29%, conflicts 0,
// no pipe saturated) proved the plateau is the LDS-roundtrip+barrier
// structure serializing operand delivery against the MFMA burst each iter.
// The DMA's global access pattern (16 rows x 64 B per wave-load) is identical
// when issued as plain global_load_dwordx4 into VGPRs, so load fragments
// DIRECT global->register: 12 coalesced loads + 32 MFMAs per iter, zero sync.
// Waves run free; the compiler software-pipelines loads across iterations
// (impossible across barriers). R5's failure mode (A-loads draining B-DMAs in
// the shared vmcnt queue) cannot recur: there are no DMAs at all.
//   - A (x rows) is read identically by the block's 4 waves -> L1 broadcast.
//   - XCD swizzle pins 4 o-tiles (2 MB limbs) per XCD L2.
//   - Q=4 limbs (scale 2^30) exact i8 GEMM, fp64 recombine + LIF in
//     REGISTERS (R7-proven arithmetic, absmax 0.0).
// Per-SIMD iter: 2 waves x 32 MFMA x 20.4 cyc = 1306 cyc; 48 KB/CU L2
// traffic = 857 cyc; loads hide under MFMA -> MFMA-bound, floor ~174 us.

constexpr int T_STEPS = 20;
constexpr int BATCH   = 1024;
constexpr int NIN     = 2048;
constexpr int NOUT    = 2048;

constexpr int    Q         = 4;
constexpr double SCALE     = 1073741824.0;     // 2^30
constexpr double INV_SCALE = 1.0 / SCALE;

constexpr size_t XI8_BYTES   = (size_t)T_STEPS * BATCH * NIN;        // 40 MB
constexpr size_t PLANE_BYTES = (size_t)NOUT * NIN;                   // 4 MB
constexpr size_t WS_NEEDED   = XI8_BYTES + (size_t)Q * PLANE_BYTES;  // 56 MB

typedef int v4i __attribute__((ext_vector_type(4)));

// ---------------------------------------------------------------- prep: x -> i8
__global__ void prep_x(const float* __restrict__ x, int8_t* __restrict__ xi) {
    const int idx = blockIdx.x * blockDim.x + threadIdx.x;   // 16 elems each
    const float4* xg = reinterpret_cast<const float4*>(x) + idx * 4;
    int8_t c[16];
#pragma unroll
    for (int q = 0; q < 4; ++q) {
        const float4 v = xg[q];
        c[q * 4 + 0] = (int8_t)(v.x != 0.0f);
        c[q * 4 + 1] = (int8_t)(v.y != 0.0f);
        c[q * 4 + 2] = (int8_t)(v.z != 0.0f);
        c[q * 4 + 3] = (int8_t)(v.w != 0.0f);
    }
    reinterpret_cast<v4i*>(xi)[idx] = *reinterpret_cast<const v4i*>(c);
}

// ------------------------------------------------- prep: W -> 4 base-256 digits
__global__ void prep_limbs(const float* __restrict__ w, int8_t* __restrict__ limbs) {
    const int idx = blockIdx.x * blockDim.x + threadIdx.x;   // 4 weights each
    const float4 wv = reinterpret_cast<const float4*>(w)[idx];
    const float wf[4] = {wv.x, wv.y, wv.z, wv.w};
    int8_t d[Q][4];
#pragma unroll
    for (int e = 0; e < 4; ++e) {
        long long M = llrint((double)wf[e] * SCALE);         // |M| < 2^30
#pragma unroll
        for (int j = 0; j < Q - 1; ++j) {
            const int dj = (int)((M + 128) & 255) - 128;
            d[j][e] = (int8_t)dj;
            M = (M - dj) >> 8;                               // exact
        }
        d[Q - 1][e] = (int8_t)M;                             // |top| <= 65
    }
#pragma unroll
    for (int j = 0; j < Q; ++j)
        reinterpret_cast<char4*>(limbs + (size_t)j * PLANE_BYTES)[idx] =
            make_char4(d[j][0], d[j][1], d[j][2], d[j][3]);
}

// ----------------------------------------- hot: i8 GEMMs, all-register, no LDS
constexpr int NKC = NIN / 64;               // 32 k-chunks of 64
constexpr int NTB = T_STEPS / 2;            // 10 t-pairs

__global__ __launch_bounds__(256, 2)
void snn_i8_direct(const int8_t* __restrict__ xi, const int8_t* __restrict__ limbs,
                   float* __restrict__ out)
{
    // XCD swizzle: 4 o-tiles pinned per XCD -> limb set 2 MB in 4 MB L2
    const int bid   = blockIdx.x;
    const int xcd   = bid & 7;
    const int sub   = bid >> 3;
    const int otile = xcd * 4 + (sub & 3);
    const int btile = sub >> 2;
    const int o0 = otile * 64, b0 = btile * 64;

    const int tid  = threadIdx.x;
    const int w    = tid >> 6;     // wave id = o j-group (16 cols)
    const int ln   = tid & 63;
    const int lm   = ln & 15;
    const int qd   = ln >> 4;

    // per-lane byte offsets (identical pattern the R4/R7 DMAs used globally)
    const size_t a_off = (size_t)(b0 + lm) * NIN + qd * 16;           // + mg*16*NIN
    const size_t b_off = (size_t)(o0 + 16 * w + lm) * NIN + qd * 16;  // + j*PLANE

    // LIF state: lane elems e = mg*4+r -> b = b0+16mg+4qd+r, o = o0+16w+lm
    double V[16], I[16];
#pragma unroll
    for (int e = 0; e < 16; ++e) { V[e] = 0.0; I[e] = 0.0; }

    const double alpha_m = 1.0 - 1.0 / 20.0;
    const double alpha_s = 1.0 - 1.0 / 5.0;
    const double dtm     = 1.0 / 20.0;

    for (int tb = 0; tb < NTB; ++tb) {
        const int8_t* x0 = xi + (size_t)(2 * tb) * BATCH * NIN + a_off;
        const int8_t* x1 = x0 + (size_t)BATCH * NIN;
        const int8_t* lb = limbs + b_off;

        v4i acc0[4][4], acc1[4][4];   // [mg][limb]
#pragma unroll
        for (int mg = 0; mg < 4; ++mg)
#pragma unroll
            for (int j = 0; j < Q; ++j) {
                acc0[mg][j] = (v4i){0, 0, 0, 0};
                acc1[mg][j] = (v4i){0, 0, 0, 0};
            }

        for (int kci = 0; kci < NKC; ++kci) {
            const int kc = kci << 6;
            // operand loads: plain coalesced global->VGPR (no LDS, no sync).
            v4i Bf[4];
#pragma unroll
            for (int j = 0; j < Q; ++j)
                Bf[j] = *reinterpret_cast<const v4i*>(
                    lb + (size_t)j * PLANE_BYTES + kc);
            v4i A0[4], A1[4];
#pragma unroll
            for (int mg = 0; mg < 4; ++mg) {
                A0[mg] = *reinterpret_cast<const v4i*>(x0 + mg * 16 * NIN + kc);
                A1[mg] = *reinterpret_cast<const v4i*>(x1 + mg * 16 * NIN + kc);
            }
#pragma unroll
            for (int mg = 0; mg < 4; ++mg)
#pragma unroll
                for (int j = 0; j < Q; ++j) {
                    acc0[mg][j] = __builtin_amdgcn_mfma_i32_16x16x64_i8(
                        A0[mg], Bf[j], acc0[mg][j], 0, 0, 0);
                    acc1[mg][j] = __builtin_amdgcn_mfma_i32_16x16x64_i8(
                        A1[mg], Bf[j], acc1[mg][j], 0, 0, 0);
                }
        }

        // recombine digits (exact fp64), LIF, emit spikes for t-pair
        const int ocol = o0 + 16 * w + lm;
#pragma unroll
        for (int tt = 0; tt < 2; ++tt) {
            const int t = 2 * tb + tt;
#pragma unroll
            for (int mg = 0; mg < 4; ++mg) {
#pragma unroll
                for (int r = 0; r < 4; ++r) {
                    const int d0 = tt ? acc1[mg][0][r] : acc0[mg][0][r];
                    const int d1 = tt ? acc1[mg][1][r] : acc0[mg][1][r];
                    const int d2 = tt ? acc1[mg][2][r] : acc0[mg][2][r];
                    const int d3 = tt ? acc1[mg][3][r] : acc0[mg][3][r];
                    double sm = (double)d3;
                    sm = sm * 256.0 + (double)d2;
                    sm = sm * 256.0 + (double)d1;
                    sm = sm * 256.0 + (double)d0;
                    const double cur = sm * INV_SCALE;

                    const int e = mg * 4 + r;
                    I[e] = alpha_s * I[e] + cur;
                    V[e] = alpha_m * V[e] + dtm * I[e];
                    const double sp = (V[e] >= 1.0) ? 1.0 : 0.0;
                    V[e] *= (1.0 - sp);

                    const int brow = b0 + 16 * mg + 4 * qd + r;
                    out[(size_t)t * BATCH * NOUT + (size_t)brow * NOUT + ocol]
                        = (float)sp;
                }
            }
        }
    }
}

// ------------------------------------ fallback: verified fp64 VALU kernel (R1)
constexpr int TBF = 64, TOF = 64, KCF = 64, LDPF = KCF + 4;

__global__ __launch_bounds__(256, 2)
void snn_fused(const float* __restrict__ x,
               const float* __restrict__ w,
               float* __restrict__ out)
{
    const int o0  = blockIdx.x * TOF;
    const int b0  = blockIdx.y * TBF;
    const int tid = threadIdx.x;
    const int tx  = tid & 15;
    const int ty  = tid >> 4;

    __shared__ float xs[TBF][LDPF];
    __shared__ float ws[TOF][LDPF];

    const int lr = tid >> 2;
    const int lc = (tid & 3) << 4;

    double V[4][4], I[4][4];
#pragma unroll
    for (int i = 0; i < 4; ++i)
#pragma unroll
        for (int j = 0; j < 4; ++j) { V[i][j] = 0.0; I[i][j] = 0.0; }

    const double alpha_m = 1.0 - 1.0 / 20.0;
    const double alpha_s = 1.0 - 1.0 / 5.0;
    const double dtm     = 1.0 / 20.0;

    for (int t = 0; t < T_STEPS; ++t) {
        const float* xt = x + (size_t)t * BATCH * NIN;
        double c[4][4];
#pragma unroll
        for (int i = 0; i < 4; ++i)
#pragma unroll
            for (int j = 0; j < 4; ++j) c[i][j] = 0.0;

        for (int kc = 0; kc < NIN; kc += KCF) {
            __syncthreads();
            {
                const float4* xg = reinterpret_cast<const float4*>(
                    xt + (size_t)(b0 + lr) * NIN + kc + lc);
                const float4* wg = reinterpret_cast<const float4*>(
                    w + (size_t)(o0 + lr) * NIN + kc + lc);
#pragma unroll
                for (int q = 0; q < 4; ++q) {
                    float4 xv = xg[q];
                    float4 wv4 = wg[q];
                    const int cbi = lc + q * 4;
                    xs[lr][cbi + 0] = xv.x;  xs[lr][cbi + 1] = xv.y;
                    xs[lr][cbi + 2] = xv.z;  xs[lr][cbi + 3] = xv.w;
                    ws[lr][cbi + 0] = wv4.x; ws[lr][cbi + 1] = wv4.y;
                    ws[lr][cbi + 2] = wv4.z; ws[lr][cbi + 3] = wv4.w;
                }
            }
            __syncthreads();

#pragma unroll 8
            for (int k = 0; k < KCF; ++k) {
                float xa[4], wa[4];
#pragma unroll
                for (int i = 0; i < 4; ++i) xa[i] = xs[ty * 4 + i][k];
#pragma unroll
                for (int j = 0; j < 4; ++j) wa[j] = ws[tx * 4 + j][k];
#pragma unroll
                for (int i = 0; i < 4; ++i)
#pragma unroll
                    for (int j = 0; j < 4; ++j)
                        c[i][j] += (double)xa[i] * (double)wa[j];
            }
        }

#pragma unroll
        for (int i = 0; i < 4; ++i) {
            float sv[4];
#pragma unroll
            for (int j = 0; j < 4; ++j) {
                I[i][j] = alpha_s * I[i][j] + c[i][j];
                V[i][j] = alpha_m * V[i][j] + dtm * I[i][j];
                const double sp = (V[i][j] >= 1.0) ? 1.0 : 0.0;
                V[i][j] *= (1.0 - sp);
                sv[j] = (float)sp;
            }
            const size_t oidx = (size_t)t * BATCH * NOUT
                              + (size_t)(b0 + ty * 4 + i) * NOUT
                              + (size_t)(o0 + tx * 4);
            *reinterpret_cast<float4*>(out + oidx) =
                make_float4(sv[0], sv[1], sv[2], sv[3]);
        }
    }
}

extern "C" void kernel_launch(void* const* d_in, const int* in_sizes, int n_in,
                              void* d_out, int out_size, void* d_ws, size_t ws_size,
                              hipStream_t stream) {
    const float* x = (const float*)d_in[0];
    const float* w = (const float*)d_in[1];
    float* out     = (float*)d_out;
    (void)in_sizes; (void)n_in; (void)out_size;

    if (ws_size >= WS_NEEDED) {
        int8_t* xi    = (int8_t*)d_ws;
        int8_t* limbs = xi + XI8_BYTES;
        prep_x<<<(int)(XI8_BYTES / 16 / 256), 256, 0, stream>>>(x, xi);
        prep_limbs<<<(int)(PLANE_BYTES / 4 / 256), 256, 0, stream>>>(w, limbs);
        snn_i8_direct<<<512, 256, 0, stream>>>(xi, limbs, out);
    } else {
        dim3 grid(NOUT / TOF, BATCH / TBF);
        snn_fused<<<grid, dim3(256), 0, stream>>>(x, w, out);
    }
}